// Round 19
// baseline (645.574 us; speedup 1.0000x reference)
//
#include <hip/hip_runtime.h>

// LSTM, B=512 x T=1024, H=100, input_size=1.
// R23 = R22 (574us) + COMPACT B + exec-masked reads.
// R22 step = 1240 cyc: MFMA ~417, VALU ~675, LDS B-read ~670 (56 b128 x
// 1KB = 57KB/step through the return path). With single-plane h, B cols
// 8-15 are PERMANENT ZEROS -> half of every read is wasted. This round:
// B stored compact [parity][kt][32][4] (cols 0-7 only); lanes col<8 read
// (512B/instr), lanes col>=8 supply bf=0 to MFMA. Same instr count, half
// the LDS data. Bit-identical numerics to R22 (absmax must stay exactly
// 4.882812e-4). Clean probe: dur drops ~60-100us if DS pipe is
// data-proportional; flat if per-instruction (then VALU-issue is the
// residual and we're near this formulation's floor).
// Structure otherwise R22: 14 waves (w0-11: 2 tiles, w12: 1, w13: out +
// x-stager), unit-major tiles, 1 barrier/step, parity-dbuf, lagged out.
// 64 blocks x 896 thr.

#define HID   100
#define TLEN  1024
#define NB    8
#define BLOCK 896
#define INSTR 1033   // in_s row stride: conflict-free
#define LOG2E   1.442695041f
#define LOG2E2  2.885390082f
#define RCP(x)  __builtin_amdgcn_rcpf(x)

typedef _Float16 half8 __attribute__((ext_vector_type(8)));
typedef float    f32x4 __attribute__((ext_vector_type(4)));

#define MFMA(A,B,C) __builtin_amdgcn_mfma_f32_16x16x32_f16((A),(B),(C),0,0,0)

static __device__ __forceinline__ unsigned packh(_Float16 a, _Float16 b) {
    return (unsigned)__builtin_bit_cast(unsigned short, a)
         | ((unsigned)__builtin_bit_cast(unsigned short, b) << 16);
}
static __device__ __forceinline__ float exp2v(float x) {
    float r;
    asm("v_exp_f32 %0, %1" : "=v"(r) : "v"(x));
    return r;
}

__global__ __launch_bounds__(BLOCK, 1)
void lstm_mfma7(
    const float* __restrict__ input,   // [B, T]
    const float* __restrict__ W_ih,    // [4H]
    const float* __restrict__ W_hh,    // [4H, H]
    const float* __restrict__ b_ih,    // [4H]
    const float* __restrict__ b_hh,    // [4H]
    const float* __restrict__ W_out,   // [H]
    const float* __restrict__ b_out,   // [1]
    float* __restrict__ out)           // [B, T]
{
    const int tid  = threadIdx.x;
    const int lane = tid & 63;
    const int w    = tid >> 6;        // wave 0..13
    const int b0   = blockIdx.x * NB;
    const int q    = lane >> 4;       // k-subgroup / D row-quad
    const int col  = lane & 15;       // B col n / A row-in-tile
    const int side = (col >> 3) & 1;  // 0: cols 0-7 (batches), 1: cols 8-15
    const int bat  = lane & 7;        // batch index

    // COMPACT B: Bc[parity][kt][(q<<3)|bat][dword], 4 KB total.
    // k = 32*kt + 8*q + 2*dw + sub. Only batch cols 0-7 stored; cols 8-15
    // of the MFMA B operand are constant-0 in registers.
    __shared__ __align__(16) unsigned Bc[2][4][32][4];
    __shared__ float in_s[NB * INSTR];                     // 33 KB

    for (int i = tid; i < NB * TLEN; i += BLOCK) {
        const int n = i >> 10, t = i & 1023;
        in_s[n * INSTR + t] = input[(b0 + n) * TLEN + t];
    }
    for (int i = tid; i < 2 * 4 * 32 * 4; i += BLOCK)
        ((unsigned*)Bc)[i] = 0u;

    // ---- tile assignment: w0-11: {2w,2w+1}; w12: {24}; w13: out ----
    const int nt = (w < 12) ? 2 : ((w == 12) ? 1 : 0);
    const int tb = 2 * w;

    // ---- A fragments, UNIT-MAJOR, single-plane f16, gate-scaled ----
    half8 A[2][4];                    // [local tile][kt]
    if (w < 13) {
        const int g = col & 3;                    // gate of this A row
        const float scl = (g == 2) ? LOG2E2 : -LOG2E;
        #pragma unroll
        for (int i = 0; i < 2; ++i) {
            if (i < nt) {
                const int m    = tb + i;
                const int u    = 4 * m + (col >> 2);   // unit of this A row
                const int wrow = HID * g + u;          // W_hh gate-major row
                #pragma unroll
                for (int kt = 0; kt < 4; ++kt) {
                    half8 hh;
                    #pragma unroll
                    for (int j = 0; j < 8; ++j) {
                        const int k = 32 * kt + 8 * q + j;
                        float v = 0.f;
                        if (k < HID)            v = W_hh[wrow * HID + k];
                        else if (k == HID)      v = b_ih[wrow] + b_hh[wrow];
                        else if (k <= HID + 2)  v = W_ih[wrow];
                        hh[j] = (_Float16)(v * scl);
                    }
                    A[i][kt] = hh;
                }
            }
        }
    } else {
        // wave 13: out tile, UNSCALED: row 0 = W_out, b_out at k=100.
        #pragma unroll
        for (int kt = 0; kt < 4; ++kt) {
            half8 hh;
            #pragma unroll
            for (int j = 0; j < 8; ++j) {
                const int k = 32 * kt + 8 * q + j;
                float v = 0.f;
                if (col == 0) {
                    if (k < HID)       v = W_out[k];
                    else if (k == HID) v = b_out[0];
                }
                hh[j] = (_Float16)v;
            }
            A[0][kt] = hh;
        }
    }

    float c0 = 0.f;                   // cell state: 1 cell/lane

    // ---- hoisted h-write base: my unit = 4*tb + q + 4*side (w12: 96+q).
    // byte: kt*512 + ((q'<<3)|bat)*16 + dw*4 + sub*2, parity stride 2048.
    int my_u = 4 * tb + q + 4 * side;
    if (w == 12) my_u = 96 + q;
    char* const wbase = (char*)Bc
        + ((my_u >> 5) * 512)
        + (((((my_u >> 3) & 3) << 3) | bat) * 16)
        + (((my_u >> 1) & 3) * 4) + ((my_u & 1) * 2);

    // ---- hoisted compact read base (col<8 lanes) ----
    const char* const rbase = (const char*)Bc + (((q << 3) | bat) * 16);

    __syncthreads();
    // prologue: x[0]+bias-one into parity 0 (k=100..102, batch cols)
    if (w == 13 && lane < NB) {
        const float xv = in_s[lane * INSTR];
        const _Float16 xh = (_Float16)xv;
        const _Float16 xl = (_Float16)(xv - (float)xh);
        uint2 dv; dv.x = packh((_Float16)1.f, xh); dv.y = packh(xl, (_Float16)0.f);
        *(uint2*)&Bc[0][3][lane][2] = dv;
    }
    __syncthreads();

    const half8 zf = {(_Float16)0.f, (_Float16)0.f, (_Float16)0.f, (_Float16)0.f,
                      (_Float16)0.f, (_Float16)0.f, (_Float16)0.f, (_Float16)0.f};

    #pragma unroll 1
    for (int t = 0; t < TLEN; ++t) {
        const int p  = t & 1;
        const int pp = p ^ 1;
        // ---- B fragments: cols 0-7 read compact LDS; cols 8-15 are 0 ----
        half8 bf0 = zf, bf1 = zf, bf2 = zf, bf3 = zf;
        if (!side) {
            const char* rb = rbase + p * 2048;
            bf0 = *(const half8*)(rb);
            bf1 = *(const half8*)(rb + 512);
            bf2 = *(const half8*)(rb + 1024);
            bf3 = *(const half8*)(rb + 1536);
        }

        if (w < 12) {
            // ---- 2 tiles, interleaved chains (8 MFMA) ----
            f32x4 D0 = {0.f,0.f,0.f,0.f}, D1 = {0.f,0.f,0.f,0.f};
            D0 = MFMA(A[0][0], bf0, D0); D1 = MFMA(A[1][0], bf0, D1);
            D0 = MFMA(A[0][1], bf1, D0); D1 = MFMA(A[1][1], bf1, D1);
            D0 = MFMA(A[0][2], bf2, D0); D1 = MFMA(A[1][2], bf2, D1);
            D0 = MFMA(A[0][3], bf3, D0); D1 = MFMA(A[1][3], bf3, D1);
            // ---- exchange: side1 lanes take tile B's gates from side0's D1
            const float r0 = __shfl_xor(D1[0], 8);
            const float r1 = __shfl_xor(D1[1], 8);
            const float r2 = __shfl_xor(D1[2], 8);
            const float r3 = __shfl_xor(D1[3], 8);
            const float g0 = side ? r0 : D0[0];
            const float g1 = side ? r1 : D0[1];
            const float g2 = side ? r2 : D0[2];
            const float g3 = side ? r3 : D0[3];
            // ---- cell (gates of unit my_u, batch bat) ----
            const float is_ = RCP(1.f + exp2v(g0));
            const float fs_ = RCP(1.f + exp2v(g1));
            const float os_ = RCP(1.f + exp2v(g3));
            const float gt_ = fmaf(-2.f, RCP(1.f + exp2v(g2)), 1.f);
            c0 = fmaf(fs_, c0, is_ * gt_);
            const float th_ = fmaf(-2.f, RCP(1.f + exp2v(LOG2E2 * c0)), 1.f);
            const _Float16 hh_ = (_Float16)(os_ * th_);
            *(unsigned short*)(wbase + pp * 2048) =
                __builtin_bit_cast(unsigned short, hh_);
        } else if (w == 12) {
            // ---- lone tile 24 (4 MFMA); side0 lanes own the cells ----
            f32x4 D0 = {0.f,0.f,0.f,0.f};
            D0 = MFMA(A[0][0], bf0, D0);
            D0 = MFMA(A[0][1], bf1, D0);
            D0 = MFMA(A[0][2], bf2, D0);
            D0 = MFMA(A[0][3], bf3, D0);
            const float is_ = RCP(1.f + exp2v(D0[0]));
            const float fs_ = RCP(1.f + exp2v(D0[1]));
            const float os_ = RCP(1.f + exp2v(D0[3]));
            const float gt_ = fmaf(-2.f, RCP(1.f + exp2v(D0[2])), 1.f);
            c0 = fmaf(fs_, c0, is_ * gt_);
            const float th_ = fmaf(-2.f, RCP(1.f + exp2v(LOG2E2 * c0)), 1.f);
            const _Float16 hh_ = (_Float16)(os_ * th_);
            if (!side)
                *(unsigned short*)(wbase + pp * 2048) =
                    __builtin_bit_cast(unsigned short, hh_);
        } else {
            // ---- wave 13: out tile (4 MFMA) -> out[t-1]; stage x[t+1] ----
            f32x4 ao = {0.f,0.f,0.f,0.f};
            ao = MFMA(A[0][0], bf0, ao);
            ao = MFMA(A[0][1], bf1, ao);
            ao = MFMA(A[0][2], bf2, ao);
            ao = MFMA(A[0][3], bf3, ao);
            if (lane < NB) {
                if (t > 0) out[(b0 + lane) * TLEN + (t - 1)] = ao[0];
                if (t + 1 < TLEN) {
                    const float xv = in_s[lane * INSTR + (t + 1)];
                    const _Float16 xh = (_Float16)xv;
                    const _Float16 xl = (_Float16)(xv - (float)xh);
                    uint2 dv; dv.x = packh((_Float16)1.f, xh);
                    dv.y = packh(xl, (_Float16)0.f);
                    *(uint2*)&Bc[pp][3][lane][2] = dv;
                }
            }
        }
        __syncthreads();   // the ONLY barrier per step
    }

    // ---- epilogue: out[.,T-1] from h[T-1] (parity 0; bias-one persists,
    // stale x at k=101,102 multiplies A-zeros) ----
    if (w == 13) {
        half8 bf0 = zf, bf1 = zf, bf2 = zf, bf3 = zf;
        if (!side) {
            bf0 = *(const half8*)(rbase);
            bf1 = *(const half8*)(rbase + 512);
            bf2 = *(const half8*)(rbase + 1024);
            bf3 = *(const half8*)(rbase + 1536);
        }
        f32x4 ao = {0.f,0.f,0.f,0.f};
        ao = MFMA(A[0][0], bf0, ao);
        ao = MFMA(A[0][1], bf1, ao);
        ao = MFMA(A[0][2], bf2, ao);
        ao = MFMA(A[0][3], bf3, ao);
        if (lane < NB) out[(b0 + lane) * TLEN + (TLEN - 1)] = ao[0];
    }
}

extern "C" void kernel_launch(void* const* d_in, const int* in_sizes, int n_in,
                              void* d_out, int out_size, void* d_ws, size_t ws_size,
                              hipStream_t stream) {
    const float* input = (const float*)d_in[0];
    const float* W_ih  = (const float*)d_in[1];
    const float* W_hh  = (const float*)d_in[2];
    const float* b_ih  = (const float*)d_in[3];
    const float* b_hh  = (const float*)d_in[4];
    const float* W_out = (const float*)d_in[5];
    const float* b_out = (const float*)d_in[6];
    float* out = (float*)d_out;

    const int B = in_sizes[0] / TLEN;  // 512
    lstm_mfma7<<<B / NB, BLOCK, 0, stream>>>(input, W_ih, W_hh, b_ih, b_hh,
                                             W_out, b_out, out);
}

// Round 20
// 585.771 us; speedup vs baseline: 1.1021x; 1.1021x over previous
//
#include <hip/hip_runtime.h>

// LSTM, B=512 x T=1024, H=100, input_size=1.
// R24 = R22 (574us, best) + s_setprio(1) around the MFMA cluster (T5).
// R23's lesson: exec-masked compact-B reads cost MORE VALU than the LDS
// return saved (645us) -> R22's full-width reads are effectively free.
// R22 decomposition: MFMA queue 504 cyc/SIMD (saturated during its phase)
// + VALU/trans 675 + overhead = 1240 measured -> phases are ADDITIVE:
// round-robin arbitration finishes all waves' MFMAs simultaneously, so all
// cells serialize behind the full queue. setprio(1) during MFMA / (0)
// during cell makes MFMA-phase waves outrank cell-phase waves -> scheduler
// amplifies jitter into a stagger -> early finishers run cells (trans pipe)
// under later waves' MFMAs (matrix pipe). Target step 1240 -> ~950.
// Everything else identical to R22 (bit-identical numerics).

#define HID   100
#define TLEN  1024
#define NB    8
#define BLOCK 896
#define INSTR 1033   // in_s row stride: conflict-free
#define LOG2E   1.442695041f
#define LOG2E2  2.885390082f
#define RCP(x)  __builtin_amdgcn_rcpf(x)

typedef _Float16 half8 __attribute__((ext_vector_type(8)));
typedef float    f32x4 __attribute__((ext_vector_type(4)));

#define MFMA(A,B,C) __builtin_amdgcn_mfma_f32_16x16x32_f16((A),(B),(C),0,0,0)

static __device__ __forceinline__ unsigned packh(_Float16 a, _Float16 b) {
    return (unsigned)__builtin_bit_cast(unsigned short, a)
         | ((unsigned)__builtin_bit_cast(unsigned short, b) << 16);
}
static __device__ __forceinline__ float exp2v(float x) {
    float r;
    asm("v_exp_f32 %0, %1" : "=v"(r) : "v"(x));
    return r;
}

__global__ __launch_bounds__(BLOCK, 1)
void lstm_mfma8(
    const float* __restrict__ input,   // [B, T]
    const float* __restrict__ W_ih,    // [4H]
    const float* __restrict__ W_hh,    // [4H, H]
    const float* __restrict__ b_ih,    // [4H]
    const float* __restrict__ b_hh,    // [4H]
    const float* __restrict__ W_out,   // [H]
    const float* __restrict__ b_out,   // [1]
    float* __restrict__ out)           // [B, T]
{
    const int tid  = threadIdx.x;
    const int lane = tid & 63;
    const int w    = tid >> 6;        // wave 0..13
    const int b0   = blockIdx.x * NB;
    const int q    = lane >> 4;       // k-subgroup / D row-quad
    const int col  = lane & 15;       // B col n / A row-in-tile
    const int side = (col >> 3) & 1;  // 0: cols 0-7 (batches), 1: cols 8-15
    const int bat  = lane & 7;        // batch index

    // B_lds[parity][kt][(q<<4)|col][dword]: k = 32*kt + 8*q + 2*dw + sub.
    // cols 0-7: h f16 (+ bias/x rows at k=100..102); cols 8-15: zeros.
    __shared__ __align__(16) unsigned B_lds[2][4][64][4];
    __shared__ float in_s[NB * INSTR];                     // 33 KB

    for (int i = tid; i < NB * TLEN; i += BLOCK) {
        const int n = i >> 10, t = i & 1023;
        in_s[n * INSTR + t] = input[(b0 + n) * TLEN + t];
    }
    for (int i = tid; i < 2 * 4 * 64 * 4; i += BLOCK)
        ((unsigned*)B_lds)[i] = 0u;

    // ---- tile assignment: w0-11: {2w,2w+1}; w12: {24}; w13: out ----
    const int nt = (w < 12) ? 2 : ((w == 12) ? 1 : 0);
    const int tb = 2 * w;

    // ---- A fragments, UNIT-MAJOR, single-plane f16, gate-scaled ----
    half8 A[2][4];                    // [local tile][kt]
    if (w < 13) {
        const int g = col & 3;                    // gate of this A row
        const float scl = (g == 2) ? LOG2E2 : -LOG2E;
        #pragma unroll
        for (int i = 0; i < 2; ++i) {
            if (i < nt) {
                const int m    = tb + i;
                const int u    = 4 * m + (col >> 2);   // unit of this A row
                const int wrow = HID * g + u;          // W_hh gate-major row
                #pragma unroll
                for (int kt = 0; kt < 4; ++kt) {
                    half8 hh;
                    #pragma unroll
                    for (int j = 0; j < 8; ++j) {
                        const int k = 32 * kt + 8 * q + j;
                        float v = 0.f;
                        if (k < HID)            v = W_hh[wrow * HID + k];
                        else if (k == HID)      v = b_ih[wrow] + b_hh[wrow];
                        else if (k <= HID + 2)  v = W_ih[wrow];
                        hh[j] = (_Float16)(v * scl);
                    }
                    A[i][kt] = hh;
                }
            }
        }
    } else {
        // wave 13: out tile, UNSCALED: row 0 = W_out, b_out at k=100.
        #pragma unroll
        for (int kt = 0; kt < 4; ++kt) {
            half8 hh;
            #pragma unroll
            for (int j = 0; j < 8; ++j) {
                const int k = 32 * kt + 8 * q + j;
                float v = 0.f;
                if (col == 0) {
                    if (k < HID)       v = W_out[k];
                    else if (k == HID) v = b_out[0];
                }
                hh[j] = (_Float16)v;
            }
            A[0][kt] = hh;
        }
    }

    float c0 = 0.f;                   // cell state: 1 cell/lane

    // ---- hoisted h-write base: my unit = 4*tb + q + 4*side (w12: 96+q).
    // byte offset: kt*1024 + ((q'<<4)|bat)*16 + dw*4 + sub*2, parity +4096.
    int my_u = 4 * tb + q + 4 * side;
    if (w == 12) my_u = 96 + q;
    char* const wbase = (char*)B_lds
        + ((my_u >> 5) * 1024)
        + (((((my_u >> 3) & 3) << 4) | bat) * 16)
        + (((my_u >> 1) & 3) * 4) + ((my_u & 1) * 2);

    __syncthreads();
    // prologue: x[0]+bias-one into parity 0, cols 0-7 (k=100..102)
    if (w == 13 && lane < NB) {
        const float xv = in_s[lane * INSTR];
        const _Float16 xh = (_Float16)xv;
        const _Float16 xl = (_Float16)(xv - (float)xh);
        uint2 dv; dv.x = packh((_Float16)1.f, xh); dv.y = packh(xl, (_Float16)0.f);
        *(uint2*)&B_lds[0][3][lane][2] = dv;
    }
    __syncthreads();

    #pragma unroll 1
    for (int t = 0; t < TLEN; ++t) {
        const int p  = t & 1;
        const int pp = p ^ 1;
        const half8 bf0 = *(const half8*)&B_lds[p][0][lane][0];
        const half8 bf1 = *(const half8*)&B_lds[p][1][lane][0];
        const half8 bf2 = *(const half8*)&B_lds[p][2][lane][0];
        const half8 bf3 = *(const half8*)&B_lds[p][3][lane][0];

        if (w < 12) {
            // ---- 2 tiles, interleaved chains (8 MFMA), prio-raised ----
            __builtin_amdgcn_s_setprio(1);
            f32x4 D0 = {0.f,0.f,0.f,0.f}, D1 = {0.f,0.f,0.f,0.f};
            D0 = MFMA(A[0][0], bf0, D0); D1 = MFMA(A[1][0], bf0, D1);
            D0 = MFMA(A[0][1], bf1, D0); D1 = MFMA(A[1][1], bf1, D1);
            D0 = MFMA(A[0][2], bf2, D0); D1 = MFMA(A[1][2], bf2, D1);
            D0 = MFMA(A[0][3], bf3, D0); D1 = MFMA(A[1][3], bf3, D1);
            __builtin_amdgcn_s_setprio(0);
            // ---- exchange: side1 lanes take tile B's gates from side0's D1
            const float r0 = __shfl_xor(D1[0], 8);
            const float r1 = __shfl_xor(D1[1], 8);
            const float r2 = __shfl_xor(D1[2], 8);
            const float r3 = __shfl_xor(D1[3], 8);
            const float g0 = side ? r0 : D0[0];
            const float g1 = side ? r1 : D0[1];
            const float g2 = side ? r2 : D0[2];
            const float g3 = side ? r3 : D0[3];
            // ---- cell (D rows ARE the 4 gates of unit my_u, batch bat) ----
            const float is_ = RCP(1.f + exp2v(g0));
            const float fs_ = RCP(1.f + exp2v(g1));
            const float os_ = RCP(1.f + exp2v(g3));
            const float gt_ = fmaf(-2.f, RCP(1.f + exp2v(g2)), 1.f);
            c0 = fmaf(fs_, c0, is_ * gt_);
            const float th_ = fmaf(-2.f, RCP(1.f + exp2v(LOG2E2 * c0)), 1.f);
            const _Float16 hh_ = (_Float16)(os_ * th_);
            *(unsigned short*)(wbase + pp * 4096) =
                __builtin_bit_cast(unsigned short, hh_);
        } else if (w == 12) {
            // ---- lone tile 24 (4 MFMA); side0 lanes own the cells ----
            __builtin_amdgcn_s_setprio(1);
            f32x4 D0 = {0.f,0.f,0.f,0.f};
            D0 = MFMA(A[0][0], bf0, D0);
            D0 = MFMA(A[0][1], bf1, D0);
            D0 = MFMA(A[0][2], bf2, D0);
            D0 = MFMA(A[0][3], bf3, D0);
            __builtin_amdgcn_s_setprio(0);
            const float is_ = RCP(1.f + exp2v(D0[0]));
            const float fs_ = RCP(1.f + exp2v(D0[1]));
            const float os_ = RCP(1.f + exp2v(D0[3]));
            const float gt_ = fmaf(-2.f, RCP(1.f + exp2v(D0[2])), 1.f);
            c0 = fmaf(fs_, c0, is_ * gt_);
            const float th_ = fmaf(-2.f, RCP(1.f + exp2v(LOG2E2 * c0)), 1.f);
            const _Float16 hh_ = (_Float16)(os_ * th_);
            if (!side)
                *(unsigned short*)(wbase + pp * 4096) =
                    __builtin_bit_cast(unsigned short, hh_);
        } else {
            // ---- wave 13: out tile (4 MFMA) -> out[t-1]; stage x[t+1] ----
            __builtin_amdgcn_s_setprio(1);
            f32x4 ao = {0.f,0.f,0.f,0.f};
            ao = MFMA(A[0][0], bf0, ao);
            ao = MFMA(A[0][1], bf1, ao);
            ao = MFMA(A[0][2], bf2, ao);
            ao = MFMA(A[0][3], bf3, ao);
            __builtin_amdgcn_s_setprio(0);
            if (lane < NB) {
                if (t > 0) out[(b0 + lane) * TLEN + (t - 1)] = ao[0];
                if (t + 1 < TLEN) {
                    const float xv = in_s[lane * INSTR + (t + 1)];
                    const _Float16 xh = (_Float16)xv;
                    const _Float16 xl = (_Float16)(xv - (float)xh);
                    uint2 dv; dv.x = packh((_Float16)1.f, xh);
                    dv.y = packh(xl, (_Float16)0.f);
                    *(uint2*)&B_lds[pp][3][lane][2] = dv;
                }
            }
        }
        __syncthreads();   // the ONLY barrier per step
    }

    // ---- epilogue: out[.,T-1] from h[T-1] (parity 0; bias-one persists,
    // stale x at k=101,102 multiplies A-zeros) ----
    if (w == 13) {
        const half8 bf0 = *(const half8*)&B_lds[0][0][lane][0];
        const half8 bf1 = *(const half8*)&B_lds[0][1][lane][0];
        const half8 bf2 = *(const half8*)&B_lds[0][2][lane][0];
        const half8 bf3 = *(const half8*)&B_lds[0][3][lane][0];
        f32x4 ao = {0.f,0.f,0.f,0.f};
        ao = MFMA(A[0][0], bf0, ao);
        ao = MFMA(A[0][1], bf1, ao);
        ao = MFMA(A[0][2], bf2, ao);
        ao = MFMA(A[0][3], bf3, ao);
        if (lane < NB) out[(b0 + lane) * TLEN + (TLEN - 1)] = ao[0];
    }
}

extern "C" void kernel_launch(void* const* d_in, const int* in_sizes, int n_in,
                              void* d_out, int out_size, void* d_ws, size_t ws_size,
                              hipStream_t stream) {
    const float* input = (const float*)d_in[0];
    const float* W_ih  = (const float*)d_in[1];
    const float* W_hh  = (const float*)d_in[2];
    const float* b_ih  = (const float*)d_in[3];
    const float* b_hh  = (const float*)d_in[4];
    const float* W_out = (const float*)d_in[5];
    const float* b_out = (const float*)d_in[6];
    float* out = (float*)d_out;

    const int B = in_sizes[0] / TLEN;  // 512
    lstm_mfma8<<<B / NB, BLOCK, 0, stream>>>(input, W_ih, W_hh, b_ih, b_hh,
                                             W_out, b_out, out);
}